// Round 11
// baseline (774.884 us; speedup 1.0000x reference)
//
#include <hip/hip_runtime.h>

#define BB 32
#define SS 128
#define LL 4096
#define KK 129
#define NST 10

typedef float v2f __attribute__((ext_vector_type(2)));

// ---------- constexpr twiddles: TW[j] = e^{-2*pi*i*j/128}, j in [0,64) ----------
constexpr double PI_D = 3.141592653589793238462643383279502884;
constexpr double red_sin(double x){ // |x| <= pi/2, Taylor to x^17
  double x2 = x*x, t = x, r = x;
  t *= -x2/6.0;   r += t;
  t *= -x2/20.0;  r += t;
  t *= -x2/42.0;  r += t;
  t *= -x2/72.0;  r += t;
  t *= -x2/110.0; r += t;
  t *= -x2/156.0; r += t;
  t *= -x2/210.0; r += t;
  t *= -x2/272.0; r += t;
  return r;
}
constexpr double csin_d(double x){
  while (x >  PI_D) x -= 2.0*PI_D;
  while (x < -PI_D) x += 2.0*PI_D;
  if (x >  PI_D*0.5)      x =  PI_D - x;
  else if (x < -PI_D*0.5) x = -PI_D - x;
  return red_sin(x);
}
constexpr double ccos_d(double x){ return csin_d(x + PI_D*0.5); }
struct TWT { float c[64]; float s[64]; };
constexpr TWT make_tw(){
  TWT t{};
  for (int j = 0; j < 64; j++){
    double a = -2.0*PI_D*(double)j/128.0;
    t.c[j] = (float)ccos_d(a);
    t.s[j] = (float)csin_d(a);
  }
  return t;
}
constexpr TWT TW = make_tw();

// LDS pad: +1 float2 per 8 -> lane-bank map 18t mod 32 (all 16 even residues, 4-way worst)
#define PHYS8(i) ((i) + ((i) >> 3))

// packed complex MAC: acc.x += xv.x*w.x + xv.y*w.y ; acc.y += xv.y*w.x - xv.x*w.y
// (same fma order/rounding as the scalar r10 code -> bit-identical)
__device__ __forceinline__ void cfma_pk(v2f& acc, v2f xv, v2f w){
  asm("v_pk_fma_f32 %0, %1, %2, %0 op_sel:[0,0,0] op_sel_hi:[1,0,1]"
      : "+v"(acc) : "v"(xv), "v"(w));
  asm("v_pk_fma_f32 %0, %1, %2, %0 op_sel:[1,1,0] op_sel_hi:[0,1,1] neg_hi:[1,0,0]"
      : "+v"(acc) : "v"(xv), "v"(w));
}

// ---------- matched filter: LDS-staged half-row + 16-slot float2 register ring ----------
// Taps via uniform scalar loads (r10); complex MACs via v_pk_fma_f32 (2 FMA/inst).
__global__ __launch_bounds__(256) void mf_kernel(const float* __restrict__ xr,
                                                 const float* __restrict__ xi,
                                                 const float* __restrict__ kr,
                                                 const float* __restrict__ ki,
                                                 float2* __restrict__ out)
{
  const int row = blockIdx.x >> 1;        // b*S + s
  const int l0  = (blockIdx.x & 1) * 2048;
  const int t   = threadIdx.x;            // 256
  __shared__ float2 xs[2456];             // xs[PHYS8(i)] = x[l0 + i - 64]

  const float* xrr = xr + (size_t)row*LL;
  const float* xir = xi + (size_t)row*LL;
  for (int i4 = t; i4 < 544; i4 += 256){  // 544 groups of 4 float2
    const int g0 = l0 - 64 + i4*4;        // first float index
    float4 a, c;
    if (g0 >= 0 && g0 + 3 < LL){
      a = *(const float4*)(xrr + g0);
      c = *(const float4*)(xir + g0);
    } else {
      float av[4], cv[4];
      #pragma unroll
      for (int e = 0; e < 4; ++e){
        const int g = g0 + e;
        const bool ok = (g >= 0 && g < LL);
        av[e] = ok ? xrr[g] : 0.0f;
        cv[e] = ok ? xir[g] : 0.0f;
      }
      a = make_float4(av[0],av[1],av[2],av[3]);
      c = make_float4(cv[0],cv[1],cv[2],cv[3]);
    }
    const int i = i4*4;
    const int p = PHYS8(i);
    xs[p]   = make_float2(a.x, c.x);
    xs[p+1] = make_float2(a.y, c.y);
    xs[p+2] = make_float2(a.z, c.z);
    xs[p+3] = make_float2(a.w, c.w);
  }
  __syncthreads();

  const int base_l = t*8;
  // ring: slot (v&15) holds (re,im) of x[l0 + t*8 + v - 64]
  v2f ring[16];
  #pragma unroll
  for (int v = 0; v < 12; v += 2){
    const float4 p = *(const float4*)(&xs[PHYS8(base_l + v)]);
    ring[v]   = (v2f){p.x, p.y};
    ring[v+1] = (v2f){p.z, p.w};
  }

  v2f acc[8];
  #pragma unroll
  for (int j = 0; j < 8; j++) acc[j] = (v2f){0.0f, 0.0f};

  #pragma unroll 1
  for (int q8 = 0; q8 < 8; ++q8){
    #pragma unroll
    for (int qq = 0; qq < 4; ++qq){
      const int q = q8*4 + qq;
      float4 p0, p1;
      const bool doref = (q < 31);
      if (doref){
        const int v0 = base_l + q*4 + 12;
        p0 = *(const float4*)(&xs[PHYS8(v0)]);
        p1 = *(const float4*)(&xs[PHYS8(v0 + 2)]);
      }
      #pragma unroll
      for (int kk = 0; kk < 4; ++kk){
        const v2f w = (v2f){ kr[q*4 + kk], ki[q*4 + kk] };  // uniform -> s_load
        #pragma unroll
        for (int j = 0; j < 8; ++j){
          const int sl = (qq*4 + kk + j) & 15;
          cfma_pk(acc[j], ring[sl], w);
        }
      }
      if (doref){
        const int s0 = (qq*4 + 12) & 15;  // 12, 0, 4, 8
        ring[s0]   = (v2f){p0.x, p0.y};
        ring[s0+1] = (v2f){p0.z, p0.w};
        ring[s0+2] = (v2f){p1.x, p1.y};
        ring[s0+3] = (v2f){p1.z, p1.w};
      }
    }
  }
  { // tap k = 128: v = 128+j -> slot j
    const v2f w = (v2f){ kr[128], ki[128] };
    #pragma unroll
    for (int j = 0; j < 8; ++j) cfma_pk(acc[j], ring[j], w);
  }

  float4* orow = (float4*)(out + (size_t)row*LL + l0 + base_l);
  #pragma unroll
  for (int q = 0; q < 4; ++q){
    orow[q] = make_float4(acc[2*q][0], acc[2*q][1], acc[2*q+1][0], acc[2*q+1][1]);
  }
}

// ---------- init ----------
__global__ void init_kernel(const float* __restrict__ wpi,
                            float* __restrict__ w_mag, float* __restrict__ w_phase,
                            float2* __restrict__ cvec, unsigned long long* __restrict__ slots,
                            float* __restrict__ out)
{
  const int i = blockIdx.x*256 + threadIdx.x;
  if (i < BB*SS){
    float wp = wpi[i];
    w_mag[i] = 1.0f;
    w_phase[i] = wp;
    float phi = atanf(wp);
    float s, c;
    sincosf(phi, &s, &c);
    cvec[i] = make_float2(c, -s);      // m = 1 exactly (softmax of equal values)
  }
  if (i < BB) slots[i] = 0ull;
  if (i == 0) out[0] = 0.0f;
}

// ---------- in-register FFT DIF stage over N points ----------
template<int SPAN, int N>
__device__ __forceinline__ void fstage(float2* v){
  #pragma unroll
  for (int b0 = 0; b0 < N; b0 += 2*SPAN){
    #pragma unroll
    for (int j = 0; j < SPAN; j++){
      const int i0 = b0 + j, i1 = b0 + j + SPAN;
      float ax = v[i0].x, ay = v[i0].y, bx = v[i1].x, by = v[i1].y;
      float sx = ax - bx, sy = ay - by;
      v[i0].x = ax + bx; v[i0].y = ay + by;
      const int tj = j * (64 / SPAN);   // W_{2*SPAN}^j = TW[tj]
      if (tj == 0){
        v[i1].x = sx; v[i1].y = sy;
      } else if (tj == 32){             // W = -i
        v[i1].x = sy; v[i1].y = -sx;
      } else {
        const float wr = TW.c[tj], wi = TW.s[tj];
        v[i1].x = sx*wr - sy*wi;
        v[i1].y = sy*wr + sx*wi;
      }
    }
  }
}

// ---------- FFT body (r2-validated, __shfl_xor form) ----------
__device__ __forceinline__ void scan_fft_tail(float2* v, int r, int tid, int l,
                                              unsigned long long* wred, int nwave,
                                              unsigned long long* slot)
{
  // stage 1 (span 64): partner = tid^2
  {
    const bool hi = (r & 2) != 0;
    const float sgn = hi ? -1.0f : 1.0f;
    const bool odd = (r & 1) != 0;
    #pragma unroll
    for (int j = 0; j < 32; ++j){
      float px = __shfl_xor(v[j].x, 2);
      float py = __shfl_xor(v[j].y, 2);
      float ux = fmaf(sgn, v[j].x, px);
      float uy = fmaf(sgn, v[j].y, py);
      float wr = hi ? (odd ? TW.s[j] : TW.c[j]) : 1.0f;   // r=3: W128^{32+j} = (s, -c)
      float wi = hi ? (odd ? -TW.c[j] : TW.s[j]) : 0.0f;
      v[j].x = ux*wr - uy*wi;
      v[j].y = uy*wr + ux*wi;
    }
  }
  // stage 2 (span 32): partner = tid^1
  {
    const bool hi = (r & 1) != 0;
    const float sgn = hi ? -1.0f : 1.0f;
    #pragma unroll
    for (int j = 0; j < 32; ++j){
      float px = __shfl_xor(v[j].x, 1);
      float py = __shfl_xor(v[j].y, 1);
      float ux = fmaf(sgn, v[j].x, px);
      float uy = fmaf(sgn, v[j].y, py);
      float wr = hi ? TW.c[2*j] : 1.0f;                   // W64^j = TW[2j]
      float wi = hi ? TW.s[2*j] : 0.0f;
      v[j].x = ux*wr - uy*wi;
      v[j].y = uy*wr + ux*wi;
    }
  }
  fstage<16,32>(v); fstage<8,32>(v); fstage<4,32>(v); fstage<2,32>(v); fstage<1,32>(v);

  float mm = 0.0f;
  #pragma unroll
  for (int j = 0; j < 32; ++j) mm = fmaxf(mm, v[j].x*v[j].x + v[j].y*v[j].y);
  mm = fmaxf(mm, __shfl_xor(mm, 1));
  mm = fmaxf(mm, __shfl_xor(mm, 2));

  unsigned long long pk = ((unsigned long long)__float_as_uint(mm) << 32) | (unsigned int)l;
  #pragma unroll
  for (int m = 4; m < 64; m <<= 1){
    unsigned long long o = __shfl_xor(pk, m);
    if (o > pk) pk = o;
  }
  if ((tid & 63) == 0) wred[tid >> 6] = pk;
  __syncthreads();
  if (tid == 0){
    unsigned long long best = wred[0];
    for (int w = 1; w < nwave; ++w) if (wred[w] > best) best = wred[w];
    atomicMax(slot, best);
  }
}

// ---------- fused transpose + iteration-0 scan (r10, validated) ----------
__global__ __launch_bounds__(256) void tr_scan_kernel(const float2* __restrict__ xmf,
                                                      float4* __restrict__ xt2,
                                                      const float2* __restrict__ cvec,
                                                      unsigned long long* __restrict__ slots)
{
  const int b = blockIdx.y;
  const int l0 = blockIdx.x * 64;
  const int tid = threadIdx.x;
  __shared__ float ldr[SS][65];
  __shared__ float ldi[SS][65];
  __shared__ float2 csh[SS];
  __shared__ unsigned long long wred[4];
  if (tid < SS) csh[tid] = cvec[b*SS + tid];

  #pragma unroll
  for (int it = 0; it < 16; ++it){
    const int flat = it*256 + tid;
    const int s  = flat >> 5;
    const int c4 = flat & 31;
    const float4 p = *(const float4*)(xmf + ((size_t)(b*SS + s))*LL + l0 + 2*c4);
    const int sw = 8*(s >> 5);
    ldr[s][(2*c4   + sw) & 63] = p.x;  ldi[s][(2*c4   + sw) & 63] = p.y;
    ldr[s][(2*c4+1 + sw) & 63] = p.z;  ldi[s][(2*c4+1 + sw) & 63] = p.w;
  }
  __syncthreads();

  float4* dst = xt2 + ((size_t)(b*256 + blockIdx.x*4) * 16) * 64;
  #pragma unroll
  for (int it = 0; it < 16; ++it){
    const int flat = it*256 + tid;
    const int lane = flat & 63;
    const int i   = (flat >> 6) & 15;
    const int lgl = flat >> 10;
    const int fl = lane >> 2, rr = lane & 3;
    const int lrow = lgl*16 + fl;
    const int s0 = rr*32 + 2*i;
    const int col = (lrow + 8*rr) & 63;
    dst[flat] = make_float4(ldr[s0][col], ldi[s0][col], ldr[s0+1][col], ldi[s0+1][col]);
  }

  const int f = tid >> 2, r = tid & 3;
  const int l = l0 + f;
  float2 v[32];
  #pragma unroll
  for (int j = 0; j < 32; ++j){
    const int rowi = r*32 + j;
    const int col = (f + 8*r) & 63;
    const float2 x = make_float2(ldr[rowi][col], ldi[rowi][col]);
    const float2 c = csh[rowi];
    v[j].x = c.x*x.x - c.y*x.y;
    v[j].y = c.x*x.y + c.y*x.x;
  }
  scan_fft_tail(v, r, tid, l, wred, 4, slots + b);
}

// ---------- scan (swizzled layout, r7 verbatim): contiguous 1KB wave-loads ----------
__global__ __launch_bounds__(256) void scan_t_kernel(const float4* __restrict__ xt2,
                                                     const float2* __restrict__ cvec,
                                                     unsigned long long* __restrict__ slots)
{
  const int b = blockIdx.y;
  const int tid = threadIdx.x;
  const int f = tid >> 2, r = tid & 3;   // 4 lanes per FFT
  const int l = blockIdx.x*64 + f;
  const int w = tid >> 6;                // wave id
  const int lg = blockIdx.x*4 + w;       // global 16-l group
  __shared__ float2 csh[SS];
  __shared__ unsigned long long wred[4];
  if (tid < SS) csh[tid] = cvec[b*SS + tid];
  __syncthreads();

  const float4* base = xt2 + ((size_t)(b*(LL/16) + lg) * 16) * 64 + (tid & 63);
  float2 v[32];
  #pragma unroll
  for (int i = 0; i < 16; ++i){          // v[j] = x[s = r*32 + j]
    const float4 p = base[i*64];
    v[2*i]   = make_float2(p.x, p.y);
    v[2*i+1] = make_float2(p.z, p.w);
  }
  #pragma unroll
  for (int j = 0; j < 32; ++j){
    const float2 c = csh[r*32 + j];
    const float2 x = v[j];
    v[j].x = c.x*x.x - c.y*x.y;
    v[j].y = c.x*x.y + c.y*x.x;
  }
  scan_fft_tail(v, r, tid, l, wred, 4, slots + b);
}

// ---------- scan (original layout, fallback if workspace too small) ----------
__global__ __launch_bounds__(512, 4) void scan_o_kernel(const float2* __restrict__ xmf,
                                                        const float2* __restrict__ cvec,
                                                        unsigned long long* __restrict__ slots)
{
  const int b = blockIdx.y;
  const int tid = threadIdx.x;
  const int l0 = blockIdx.x * 128;
  __shared__ float2 csh[SS];
  __shared__ float2 xsh[64][130];
  __shared__ unsigned long long wred[8];
  if (tid < SS) csh[tid] = cvec[b*SS + tid];

  const int f = tid >> 2, r = tid & 3;
  float2 v[32];

  #pragma unroll 1
  for (int h = 0; h < 2; ++h){
    __syncthreads();
    const float2* src = xmf + ((size_t)(b*SS + h*64))*LL + l0;
    #pragma unroll
    for (int it = 0; it < 8; ++it){
      const int flat = it*512 + tid;
      const int s1 = flat >> 6;
      const int c4 = flat & 63;
      const float4 vv = *(const float4*)(src + (size_t)s1*LL + c4*2);
      *(float4*)(&xsh[s1][c4*2]) = vv;
    }
    __syncthreads();
    if ((r >> 1) == h){
      #pragma unroll
      for (int j = 0; j < 32; ++j){
        const int rowi = (r & 1)*32 + j;
        const float2 x = xsh[rowi][f];
        const float2 c = csh[r*32 + j];
        v[j].x = c.x*x.x - c.y*x.y;
        v[j].y = c.x*x.y + c.y*x.x;
      }
    }
  }
  scan_fft_tail(v, r, tid, l0 + f, wred, 8, slots + b);
}

// ---------- wave + block (256 thr / 4 waves) reductions ----------
__device__ __forceinline__ float wredsum(float v){
  #pragma unroll
  for (int m = 1; m < 64; m <<= 1) v += __shfl_xor(v, m);
  return v;
}
__device__ __forceinline__ float wredmax(float v){
  #pragma unroll
  for (int m = 1; m < 64; m <<= 1) v = fmaxf(v, __shfl_xor(v, m));
  return v;
}
__device__ __forceinline__ float bsum256(float v, float* red4, int t){
  v = wredsum(v);
  __syncthreads();
  if ((t & 63) == 0) red4[t >> 6] = v;
  __syncthreads();
  return red4[0] + red4[1] + red4[2] + red4[3];
}
__device__ __forceinline__ float bmax256(float v, float* red4, int t){
  v = wredmax(v);
  __syncthreads();
  if ((t & 63) == 0) red4[t >> 6] = v;
  __syncthreads();
  return fmaxf(fmaxf(red4[0], red4[1]), fmaxf(red4[2], red4[3]));
}

// ---------- per-step gradient + update (or final SNR); one block per b, 256 threads ----------
__global__ __launch_bounds__(256) void step_kernel(const float2* __restrict__ xmf,
                                                   float* __restrict__ w_mag,
                                                   float* __restrict__ w_phase,
                                                   float2* __restrict__ cvec,
                                                   unsigned long long* __restrict__ slots,
                                                   const float* __restrict__ lsm,
                                                   const float* __restrict__ lsp,
                                                   int stepi, int isFinal,
                                                   float* __restrict__ out)
{
  const int b = blockIdx.x, t = threadIdx.x;
  const int s = t >> 1, h = t & 1;
  __shared__ float2 ysh[SS];
  __shared__ float twc[SS], tws[SS];
  __shared__ float red4[4];
  __shared__ float speak;
  __shared__ int sidx;

  const int rbin = (int)(slots[b] & 0xffffffffull);
  const float wm0 = w_mag[b*SS + s];
  const float wp0 = w_phase[b*SS + s];
  const float2 xc = xmf[((size_t)(b*SS + s))*LL + rbin];
  float phi = atanf(wp0);
  float sph, cph;
  sincosf(phi, &sph, &cph);
  {
    int id = t & 127;
    float sv, cv;
    sincosf((float)(2.0*PI_D/128.0) * (float)id, &sv, &cv);
    twc[id] = cv; tws[id] = -sv;
  }
  float mx = bmax256(wm0, red4, t);
  float ex = expf(wm0 - mx);
  float sm = bsum256(ex, red4, t) * 0.5f;
  float m = 128.0f * ex / sm;
  float cre = m*cph, cim = -m*sph;
  ysh[s] = make_float2(cre*xc.x - cim*xc.y, cre*xc.y + cim*xc.x);
  __syncthreads();

  const int k = s;
  float Fr = 0.0f, Fi = 0.0f;
  #pragma unroll 8
  for (int q = 0; q < 64; ++q){
    int s2 = h*64 + q;
    int id = (k*s2) & 127;
    float wr = twc[id], wi = tws[id];
    float2 ys = ysh[s2];
    Fr += wr*ys.x - wi*ys.y;
    Fi += wr*ys.y + wi*ys.x;
  }
  Fr += __shfl_xor(Fr, 1);
  Fi += __shfl_xor(Fi, 1);
  const int u = (k + 64) & 127;
  float colu = Fr*Fr + Fi*Fi;

  float total = bsum256(colu, red4, t) * 0.5f;
  float zre = bsum256(colu * twc[u], red4, t) * 0.5f;
  float zim = bsum256(colu * (-tws[u]), red4, t) * 0.5f;
  if (t == 0){
    float ang = atan2f(zim, zre);
    float pidx = ang * (128.0f/(2.0f*(float)PI_D));
    sidx = ((int)rintf(pidx)) & 127;
  }
  __syncthreads();
  const int idx = sidx;
  if (u == idx && h == 0) speak = colu;
  __syncthreads();
  const float peak = speak;
  const float noise = (total - peak) * (1.0f/127.0f);

  if (isFinal){
    if (t == 0) atomicAdd(out, 10.0f*(log10f(peak) - log10f(noise)) * (1.0f/(float)BB));
    return;
  }

  constexpr float C10 = 4.342944819032518f;
  float g = (u == idx) ? (C10/peak) : (-C10/(127.0f*noise));
  __syncthreads();
  ysh[k] = make_float2(2.0f*g*Fr, 2.0f*g*Fi);
  __syncthreads();

  float Tr = 0.0f, Ti = 0.0f;
  #pragma unroll 8
  for (int q = 0; q < 64; ++q){
    int kk = h*64 + q;
    int id = (s*kk) & 127;
    float wr = twc[id], wi = -tws[id];
    float2 G = ysh[kk];
    Tr += wr*G.x - wi*G.y;
    Ti += wr*G.y + wi*G.x;
  }
  Tr += __shfl_xor(Tr, 1);
  Ti += __shfl_xor(Ti, 1);

  float Hr = xc.x*Tr + xc.y*Ti;
  float Hi = xc.x*Ti - xc.y*Tr;
  float dm   = Hr*cph - Hi*sph;
  float dphi = -m*(Hr*sph + Hi*cph);
  float S1 = bsum256(m*dm, red4, t) * 0.5f;
  float gwm = m*(dm - S1*(1.0f/128.0f));
  float gwp = dphi / (1.0f + wp0*wp0);

  constexpr float LN10 = 2.302585092994046f;
  float lrm = expf(lsm[s*NST + stepi] * LN10);
  float lrp = expf(lsp[s*NST + stepi] * LN10);
  float wm1 = wm0 + lrm*gwm;
  float wp1 = wp0 + lrp*gwp;
  if (h == 0){
    w_mag[b*SS + s] = wm1;
    w_phase[b*SS + s] = wp1;
  }

  float mx2 = bmax256(wm1, red4, t);
  float ex2 = expf(wm1 - mx2);
  float sm2 = bsum256(ex2, red4, t) * 0.5f;
  float m2 = 128.0f * ex2 / sm2;
  float phi2 = atanf(wp1);
  float s2v, c2v;
  sincosf(phi2, &s2v, &c2v);
  if (h == 0) cvec[b*SS + s] = make_float2(m2*c2v, -m2*s2v);
  if (t == 0) slots[b] = 0ull;
}

extern "C" void kernel_launch(void* const* d_in, const int* in_sizes, int n_in,
                              void* d_out, int out_size, void* d_ws, size_t ws_size,
                              hipStream_t stream)
{
  const float* x_re = (const float*)d_in[0];
  const float* x_im = (const float*)d_in[1];
  const float* k_re = (const float*)d_in[2];
  const float* k_im = (const float*)d_in[3];
  const float* lsm  = (const float*)d_in[4];
  const float* lsp  = (const float*)d_in[5];
  const float* wpi  = (const float*)d_in[6];
  float* out = (float*)d_out;

  char* ws = (char*)d_ws;
  size_t off = 0;
  float2* xmf = (float2*)(ws + off);                 off += (size_t)BB*SS*LL*sizeof(float2);
  unsigned long long* slots = (unsigned long long*)(ws + off); off += 256;
  float* w_mag   = (float*)(ws + off);               off += (size_t)BB*SS*4;
  float* w_phase = (float*)(ws + off);               off += (size_t)BB*SS*4;
  float2* cvec   = (float2*)(ws + off);              off += (size_t)BB*SS*8;
  const size_t off_base = off;
  float4* xt2 = (float4*)(ws + off);                 off += (size_t)BB*SS*LL*sizeof(float2);
  const int useT = (ws_size >= off) ? 1 : 0;
  if (ws_size < off_base) return;   // insufficient scratch -> fail visibly

  mf_kernel<<<BB*SS*2, 256, 0, stream>>>(x_re, x_im, k_re, k_im, xmf);
  init_kernel<<<(BB*SS + 255)/256, 256, 0, stream>>>(wpi, w_mag, w_phase, cvec, slots, out);

  if (useT){
    // fused transpose + iteration-0 scan
    tr_scan_kernel<<<dim3(LL/64, BB), 256, 0, stream>>>(xmf, xt2, cvec, slots);
    step_kernel<<<BB, 256, 0, stream>>>(xmf, w_mag, w_phase, cvec, slots, lsm, lsp, 0, 0, out);
    for (int i = 1; i < NST; i++){
      scan_t_kernel<<<dim3(LL/64, BB), 256, 0, stream>>>(xt2, cvec, slots);
      step_kernel<<<BB, 256, 0, stream>>>(xmf, w_mag, w_phase, cvec, slots, lsm, lsp, i, 0, out);
    }
    scan_t_kernel<<<dim3(LL/64, BB), 256, 0, stream>>>(xt2, cvec, slots);
    step_kernel<<<BB, 256, 0, stream>>>(xmf, w_mag, w_phase, cvec, slots, lsm, lsp, 0, 1, out);
  } else {
    for (int i = 0; i < NST; i++){
      scan_o_kernel<<<dim3(LL/128, BB), 512, 0, stream>>>(xmf, cvec, slots);
      step_kernel<<<BB, 256, 0, stream>>>(xmf, w_mag, w_phase, cvec, slots, lsm, lsp, i, 0, out);
    }
    scan_o_kernel<<<dim3(LL/128, BB), 512, 0, stream>>>(xmf, cvec, slots);
    step_kernel<<<BB, 256, 0, stream>>>(xmf, w_mag, w_phase, cvec, slots, lsm, lsp, 0, 1, out);
  }
}

// Round 12
// 759.053 us; speedup vs baseline: 1.0209x; 1.0209x over previous
//
#include <hip/hip_runtime.h>

#define BB 32
#define SS 128
#define LL 4096
#define KK 129
#define NST 10

typedef float v2f __attribute__((ext_vector_type(2)));

// ---------- constexpr twiddles: TW[j] = e^{-2*pi*i*j/128}, j in [0,64) ----------
constexpr double PI_D = 3.141592653589793238462643383279502884;
constexpr double red_sin(double x){ // |x| <= pi/2, Taylor to x^17
  double x2 = x*x, t = x, r = x;
  t *= -x2/6.0;   r += t;
  t *= -x2/20.0;  r += t;
  t *= -x2/42.0;  r += t;
  t *= -x2/72.0;  r += t;
  t *= -x2/110.0; r += t;
  t *= -x2/156.0; r += t;
  t *= -x2/210.0; r += t;
  t *= -x2/272.0; r += t;
  return r;
}
constexpr double csin_d(double x){
  while (x >  PI_D) x -= 2.0*PI_D;
  while (x < -PI_D) x += 2.0*PI_D;
  if (x >  PI_D*0.5)      x =  PI_D - x;
  else if (x < -PI_D*0.5) x = -PI_D - x;
  return red_sin(x);
}
constexpr double ccos_d(double x){ return csin_d(x + PI_D*0.5); }
struct TWT { float c[64]; float s[64]; };
constexpr TWT make_tw(){
  TWT t{};
  for (int j = 0; j < 64; j++){
    double a = -2.0*PI_D*(double)j/128.0;
    t.c[j] = (float)ccos_d(a);
    t.s[j] = (float)csin_d(a);
  }
  return t;
}
constexpr TWT TW = make_tw();

// LDS pads
#define PHYS8(i)  ((i) + ((i) >> 3))    // +1 fl2 per 8 (used where base stride is 8)
#define PHYS16(i) ((i) + ((i) >> 4))    // +1 fl2 per 16 (t*16 stride -> 2t mod 32 banks, 4-way worst)

// packed complex MAC: acc.x += xv.x*w.x + xv.y*w.y ; acc.y += xv.y*w.x - xv.x*w.y
__device__ __forceinline__ void cfma_pk(v2f& acc, v2f xv, v2f w){
  asm("v_pk_fma_f32 %0, %1, %2, %0 op_sel:[0,0,0] op_sel_hi:[1,0,1]"
      : "+v"(acc) : "v"(xv), "v"(w));
  asm("v_pk_fma_f32 %0, %1, %2, %0 op_sel:[1,1,0] op_sel_hi:[0,1,1] neg_hi:[1,0,0]"
      : "+v"(acc) : "v"(xv), "v"(w));
}

// ---------- matched filter: full row per block, 32-slot ring, 16 outputs/thread ----------
__global__ __launch_bounds__(256) void mf_kernel(const float* __restrict__ xr,
                                                 const float* __restrict__ xi,
                                                 const float* __restrict__ kr,
                                                 const float* __restrict__ ki,
                                                 float2* __restrict__ out)
{
  const int row = blockIdx.x;             // b*S + s
  const int t   = threadIdx.x;            // 256
  __shared__ float2 xs[4488];             // xs[PHYS16(i)] = x[i - 64], i in [0, 4224)

  const float* xrr = xr + (size_t)row*LL;
  const float* xir = xi + (size_t)row*LL;
  for (int i4 = t; i4 < 1056; i4 += 256){ // 1056 groups of 4 float2
    const int g0 = i4*4 - 64;             // first float index
    float4 a, c;
    if (g0 >= 0 && g0 + 3 < LL){
      a = *(const float4*)(xrr + g0);
      c = *(const float4*)(xir + g0);
    } else {
      float av[4], cv[4];
      #pragma unroll
      for (int e = 0; e < 4; ++e){
        const int g = g0 + e;
        const bool ok = (g >= 0 && g < LL);
        av[e] = ok ? xrr[g] : 0.0f;
        cv[e] = ok ? xir[g] : 0.0f;
      }
      a = make_float4(av[0],av[1],av[2],av[3]);
      c = make_float4(cv[0],cv[1],cv[2],cv[3]);
    }
    const int p = PHYS16(i4*4);           // i4*4 % 16 in {0,4,8,12}: group stays in pad block
    xs[p]   = make_float2(a.x, c.x);
    xs[p+1] = make_float2(a.y, c.y);
    xs[p+2] = make_float2(a.z, c.z);
    xs[p+3] = make_float2(a.w, c.w);
  }
  __syncthreads();

  const int base_l = t*16;                // logical fl2 index of v=0
  // ring: slot (v&31) holds (re,im) of x[t*16 + v - 64]
  v2f ring[32];
  #pragma unroll
  for (int v = 0; v < 28; v += 2){        // preload v in [0,28)
    const float4 p = *(const float4*)(&xs[PHYS16(base_l + v)]);
    ring[v]   = (v2f){p.x, p.y};
    ring[v+1] = (v2f){p.z, p.w};
  }

  v2f acc[16];
  #pragma unroll
  for (int j = 0; j < 16; j++) acc[j] = (v2f){0.0f, 0.0f};

  // 32 chunks of 4 taps; chunk q reads v in [q*4, q*4+19); refill fills [q*4+28, q*4+32)
  #pragma unroll 1
  for (int q16 = 0; q16 < 4; ++q16){
    #pragma unroll
    for (int qh = 0; qh < 2; ++qh){
      #pragma unroll
      for (int qq = 0; qq < 4; ++qq){
        const int q = q16*8 + qh*4 + qq;
        float4 p0, p1;
        const bool doref = (q < 29);
        if (doref){
          const int v0 = base_l + q*4 + 28;
          p0 = *(const float4*)(&xs[PHYS16(v0)]);
          p1 = *(const float4*)(&xs[PHYS16(v0 + 2)]);
        }
        #pragma unroll
        for (int kk = 0; kk < 4; ++kk){
          const v2f w = (v2f){ kr[q*4 + kk], ki[q*4 + kk] };  // uniform -> s_load
          #pragma unroll
          for (int j = 0; j < 16; ++j){
            const int sl = (qh*16 + qq*4 + kk + j) & 31;      // == (q*4+kk+j)&31
            cfma_pk(acc[j], ring[sl], w);
          }
        }
        if (doref){
          const int s0 = (qh*16 + qq*4 + 28) & 31;  // in {28,0,4,...,24}, no wrap in +3
          ring[s0]   = (v2f){p0.x, p0.y};
          ring[s0+1] = (v2f){p0.z, p0.w};
          ring[s0+2] = (v2f){p1.x, p1.y};
          ring[s0+3] = (v2f){p1.z, p1.w};
        }
      }
    }
  }
  { // tap k = 128: v = 128+j -> slot j
    const v2f w = (v2f){ kr[128], ki[128] };
    #pragma unroll
    for (int j = 0; j < 16; ++j) cfma_pk(acc[j], ring[j], w);
  }

  float4* orow = (float4*)(out + (size_t)row*LL + base_l);
  #pragma unroll
  for (int q = 0; q < 8; ++q){
    orow[q] = make_float4(acc[2*q][0], acc[2*q][1], acc[2*q+1][0], acc[2*q+1][1]);
  }
}

// ---------- init ----------
__global__ void init_kernel(const float* __restrict__ wpi,
                            float* __restrict__ w_mag, float* __restrict__ w_phase,
                            float2* __restrict__ cvec, unsigned long long* __restrict__ slots,
                            float* __restrict__ out)
{
  const int i = blockIdx.x*256 + threadIdx.x;
  if (i < BB*SS){
    float wp = wpi[i];
    w_mag[i] = 1.0f;
    w_phase[i] = wp;
    float phi = atanf(wp);
    float s, c;
    sincosf(phi, &s, &c);
    cvec[i] = make_float2(c, -s);      // m = 1 exactly (softmax of equal values)
  }
  if (i < BB) slots[i] = 0ull;
  if (i == 0) out[0] = 0.0f;
}

// ---------- in-register FFT DIF stage over N points ----------
template<int SPAN, int N>
__device__ __forceinline__ void fstage(float2* v){
  #pragma unroll
  for (int b0 = 0; b0 < N; b0 += 2*SPAN){
    #pragma unroll
    for (int j = 0; j < SPAN; j++){
      const int i0 = b0 + j, i1 = b0 + j + SPAN;
      float ax = v[i0].x, ay = v[i0].y, bx = v[i1].x, by = v[i1].y;
      float sx = ax - bx, sy = ay - by;
      v[i0].x = ax + bx; v[i0].y = ay + by;
      const int tj = j * (64 / SPAN);   // W_{2*SPAN}^j = TW[tj]
      if (tj == 0){
        v[i1].x = sx; v[i1].y = sy;
      } else if (tj == 32){             // W = -i
        v[i1].x = sy; v[i1].y = -sx;
      } else {
        const float wr = TW.c[tj], wi = TW.s[tj];
        v[i1].x = sx*wr - sy*wi;
        v[i1].y = sy*wr + sx*wi;
      }
    }
  }
}

// ---------- FFT body (r2-validated, __shfl_xor form) ----------
__device__ __forceinline__ void scan_fft_tail(float2* v, int r, int tid, int l,
                                              unsigned long long* wred, int nwave,
                                              unsigned long long* slot)
{
  // stage 1 (span 64): partner = tid^2
  {
    const bool hi = (r & 2) != 0;
    const float sgn = hi ? -1.0f : 1.0f;
    const bool odd = (r & 1) != 0;
    #pragma unroll
    for (int j = 0; j < 32; ++j){
      float px = __shfl_xor(v[j].x, 2);
      float py = __shfl_xor(v[j].y, 2);
      float ux = fmaf(sgn, v[j].x, px);
      float uy = fmaf(sgn, v[j].y, py);
      float wr = hi ? (odd ? TW.s[j] : TW.c[j]) : 1.0f;   // r=3: W128^{32+j} = (s, -c)
      float wi = hi ? (odd ? -TW.c[j] : TW.s[j]) : 0.0f;
      v[j].x = ux*wr - uy*wi;
      v[j].y = uy*wr + ux*wi;
    }
  }
  // stage 2 (span 32): partner = tid^1
  {
    const bool hi = (r & 1) != 0;
    const float sgn = hi ? -1.0f : 1.0f;
    #pragma unroll
    for (int j = 0; j < 32; ++j){
      float px = __shfl_xor(v[j].x, 1);
      float py = __shfl_xor(v[j].y, 1);
      float ux = fmaf(sgn, v[j].x, px);
      float uy = fmaf(sgn, v[j].y, py);
      float wr = hi ? TW.c[2*j] : 1.0f;                   // W64^j = TW[2j]
      float wi = hi ? TW.s[2*j] : 0.0f;
      v[j].x = ux*wr - uy*wi;
      v[j].y = uy*wr + ux*wi;
    }
  }
  fstage<16,32>(v); fstage<8,32>(v); fstage<4,32>(v); fstage<2,32>(v); fstage<1,32>(v);

  float mm = 0.0f;
  #pragma unroll
  for (int j = 0; j < 32; ++j) mm = fmaxf(mm, v[j].x*v[j].x + v[j].y*v[j].y);
  mm = fmaxf(mm, __shfl_xor(mm, 1));
  mm = fmaxf(mm, __shfl_xor(mm, 2));

  unsigned long long pk = ((unsigned long long)__float_as_uint(mm) << 32) | (unsigned int)l;
  #pragma unroll
  for (int m = 4; m < 64; m <<= 1){
    unsigned long long o = __shfl_xor(pk, m);
    if (o > pk) pk = o;
  }
  if ((tid & 63) == 0) wred[tid >> 6] = pk;
  __syncthreads();
  if (tid == 0){
    unsigned long long best = wred[0];
    for (int w = 1; w < nwave; ++w) if (wred[w] > best) best = wred[w];
    atomicMax(slot, best);
  }
}

// ---------- fused transpose + iteration-0 scan (r10, validated) ----------
__global__ __launch_bounds__(256) void tr_scan_kernel(const float2* __restrict__ xmf,
                                                      float4* __restrict__ xt2,
                                                      const float2* __restrict__ cvec,
                                                      unsigned long long* __restrict__ slots)
{
  const int b = blockIdx.y;
  const int l0 = blockIdx.x * 64;
  const int tid = threadIdx.x;
  __shared__ float ldr[SS][65];
  __shared__ float ldi[SS][65];
  __shared__ float2 csh[SS];
  __shared__ unsigned long long wred[4];
  if (tid < SS) csh[tid] = cvec[b*SS + tid];

  #pragma unroll
  for (int it = 0; it < 16; ++it){
    const int flat = it*256 + tid;
    const int s  = flat >> 5;
    const int c4 = flat & 31;
    const float4 p = *(const float4*)(xmf + ((size_t)(b*SS + s))*LL + l0 + 2*c4);
    const int sw = 8*(s >> 5);
    ldr[s][(2*c4   + sw) & 63] = p.x;  ldi[s][(2*c4   + sw) & 63] = p.y;
    ldr[s][(2*c4+1 + sw) & 63] = p.z;  ldi[s][(2*c4+1 + sw) & 63] = p.w;
  }
  __syncthreads();

  float4* dst = xt2 + ((size_t)(b*256 + blockIdx.x*4) * 16) * 64;
  #pragma unroll
  for (int it = 0; it < 16; ++it){
    const int flat = it*256 + tid;
    const int lane = flat & 63;
    const int i   = (flat >> 6) & 15;
    const int lgl = flat >> 10;
    const int fl = lane >> 2, rr = lane & 3;
    const int lrow = lgl*16 + fl;
    const int s0 = rr*32 + 2*i;
    const int col = (lrow + 8*rr) & 63;
    dst[flat] = make_float4(ldr[s0][col], ldi[s0][col], ldr[s0+1][col], ldi[s0+1][col]);
  }

  const int f = tid >> 2, r = tid & 3;
  const int l = l0 + f;
  float2 v[32];
  #pragma unroll
  for (int j = 0; j < 32; ++j){
    const int rowi = r*32 + j;
    const int col = (f + 8*r) & 63;
    const float2 x = make_float2(ldr[rowi][col], ldi[rowi][col]);
    const float2 c = csh[rowi];
    v[j].x = c.x*x.x - c.y*x.y;
    v[j].y = c.x*x.y + c.y*x.x;
  }
  scan_fft_tail(v, r, tid, l, wred, 4, slots + b);
}

// ---------- scan (swizzled layout, r7 verbatim): contiguous 1KB wave-loads ----------
__global__ __launch_bounds__(256) void scan_t_kernel(const float4* __restrict__ xt2,
                                                     const float2* __restrict__ cvec,
                                                     unsigned long long* __restrict__ slots)
{
  const int b = blockIdx.y;
  const int tid = threadIdx.x;
  const int f = tid >> 2, r = tid & 3;   // 4 lanes per FFT
  const int l = blockIdx.x*64 + f;
  const int w = tid >> 6;                // wave id
  const int lg = blockIdx.x*4 + w;       // global 16-l group
  __shared__ float2 csh[SS];
  __shared__ unsigned long long wred[4];
  if (tid < SS) csh[tid] = cvec[b*SS + tid];
  __syncthreads();

  const float4* base = xt2 + ((size_t)(b*(LL/16) + lg) * 16) * 64 + (tid & 63);
  float2 v[32];
  #pragma unroll
  for (int i = 0; i < 16; ++i){          // v[j] = x[s = r*32 + j]
    const float4 p = base[i*64];
    v[2*i]   = make_float2(p.x, p.y);
    v[2*i+1] = make_float2(p.z, p.w);
  }
  #pragma unroll
  for (int j = 0; j < 32; ++j){
    const float2 c = csh[r*32 + j];
    const float2 x = v[j];
    v[j].x = c.x*x.x - c.y*x.y;
    v[j].y = c.x*x.y + c.y*x.x;
  }
  scan_fft_tail(v, r, tid, l, wred, 4, slots + b);
}

// ---------- scan (original layout, fallback if workspace too small) ----------
__global__ __launch_bounds__(512, 4) void scan_o_kernel(const float2* __restrict__ xmf,
                                                        const float2* __restrict__ cvec,
                                                        unsigned long long* __restrict__ slots)
{
  const int b = blockIdx.y;
  const int tid = threadIdx.x;
  const int l0 = blockIdx.x * 128;
  __shared__ float2 csh[SS];
  __shared__ float2 xsh[64][130];
  __shared__ unsigned long long wred[8];
  if (tid < SS) csh[tid] = cvec[b*SS + tid];

  const int f = tid >> 2, r = tid & 3;
  float2 v[32];

  #pragma unroll 1
  for (int h = 0; h < 2; ++h){
    __syncthreads();
    const float2* src = xmf + ((size_t)(b*SS + h*64))*LL + l0;
    #pragma unroll
    for (int it = 0; it < 8; ++it){
      const int flat = it*512 + tid;
      const int s1 = flat >> 6;
      const int c4 = flat & 63;
      const float4 vv = *(const float4*)(src + (size_t)s1*LL + c4*2);
      *(float4*)(&xsh[s1][c4*2]) = vv;
    }
    __syncthreads();
    if ((r >> 1) == h){
      #pragma unroll
      for (int j = 0; j < 32; ++j){
        const int rowi = (r & 1)*32 + j;
        const float2 x = xsh[rowi][f];
        const float2 c = csh[r*32 + j];
        v[j].x = c.x*x.x - c.y*x.y;
        v[j].y = c.x*x.y + c.y*x.x;
      }
    }
  }
  scan_fft_tail(v, r, tid, l0 + f, wred, 8, slots + b);
}

// ---------- wave + block (256 thr / 4 waves) reductions ----------
__device__ __forceinline__ float wredsum(float v){
  #pragma unroll
  for (int m = 1; m < 64; m <<= 1) v += __shfl_xor(v, m);
  return v;
}
__device__ __forceinline__ float wredmax(float v){
  #pragma unroll
  for (int m = 1; m < 64; m <<= 1) v = fmaxf(v, __shfl_xor(v, m));
  return v;
}
__device__ __forceinline__ float bsum256(float v, float* red, int t){
  v = wredsum(v);
  __syncthreads();
  if ((t & 63) == 0) red[t >> 6] = v;
  __syncthreads();
  return red[0] + red[1] + red[2] + red[3];
}
__device__ __forceinline__ float bmax256(float v, float* red, int t){
  v = wredmax(v);
  __syncthreads();
  if ((t & 63) == 0) red[t >> 6] = v;
  __syncthreads();
  return fmaxf(fmaxf(red[0], red[1]), fmaxf(red[2], red[3]));
}
// fused triple sum: per-component summation order identical to bsum256 (bit-exact)
__device__ __forceinline__ void bsum3_256(float a0, float a1, float a2,
                                          float* red12, int t,
                                          float& s0, float& s1, float& s2){
  #pragma unroll
  for (int m = 1; m < 64; m <<= 1){
    a0 += __shfl_xor(a0, m);
    a1 += __shfl_xor(a1, m);
    a2 += __shfl_xor(a2, m);
  }
  __syncthreads();
  if ((t & 63) == 0){
    const int w = t >> 6;
    red12[w] = a0; red12[w+4] = a1; red12[w+8] = a2;
  }
  __syncthreads();
  s0 = red12[0]+red12[1]+red12[2]+red12[3];
  s1 = red12[4]+red12[5]+red12[6]+red12[7];
  s2 = red12[8]+red12[9]+red12[10]+red12[11];
}

// ---------- per-step gradient + update (or final SNR); one block per b, 256 threads ----------
__global__ __launch_bounds__(256) void step_kernel(const float2* __restrict__ xmf,
                                                   float* __restrict__ w_mag,
                                                   float* __restrict__ w_phase,
                                                   float2* __restrict__ cvec,
                                                   unsigned long long* __restrict__ slots,
                                                   const float* __restrict__ lsm,
                                                   const float* __restrict__ lsp,
                                                   int stepi, int isFinal,
                                                   float* __restrict__ out)
{
  const int b = blockIdx.x, t = threadIdx.x;
  const int s = t >> 1, h = t & 1;
  __shared__ float2 ysh[SS];
  __shared__ float twc[SS], tws[SS];
  __shared__ float red12[12];
  __shared__ float speak;
  __shared__ int sidx;

  const int rbin = (int)(slots[b] & 0xffffffffull);
  const float wm0 = w_mag[b*SS + s];
  const float wp0 = w_phase[b*SS + s];
  const float2 xc = xmf[((size_t)(b*SS + s))*LL + rbin];
  float phi = atanf(wp0);
  float sph, cph;
  sincosf(phi, &sph, &cph);
  {
    // e^{-2 pi i id/128} from the constexpr table (id>=64: negate the id-64 entry)
    const int id = t & 127;
    const int lo = id & 63;
    const float sgn2 = (id < 64) ? 1.0f : -1.0f;
    twc[id] = sgn2 * TW.c[lo];
    tws[id] = sgn2 * TW.s[lo];
  }
  float mx = bmax256(wm0, red12, t);
  float ex = expf(wm0 - mx);
  float sm = bsum256(ex, red12, t) * 0.5f;
  float m = 128.0f * ex / sm;
  float cre = m*cph, cim = -m*sph;
  ysh[s] = make_float2(cre*xc.x - cim*xc.y, cre*xc.y + cim*xc.x);
  __syncthreads();

  const int k = s;
  float Fr = 0.0f, Fi = 0.0f;
  #pragma unroll 8
  for (int q = 0; q < 64; ++q){
    int s2 = h*64 + q;
    int id = (k*s2) & 127;
    float wr = twc[id], wi = tws[id];
    float2 ys = ysh[s2];
    Fr += wr*ys.x - wi*ys.y;
    Fi += wr*ys.y + wi*ys.x;
  }
  Fr += __shfl_xor(Fr, 1);
  Fi += __shfl_xor(Fi, 1);
  const int u = (k + 64) & 127;
  float colu = Fr*Fr + Fi*Fi;

  float total, zre, zim;
  bsum3_256(colu, colu * twc[u], colu * (-tws[u]), red12, t, total, zre, zim);
  total *= 0.5f; zre *= 0.5f; zim *= 0.5f;
  if (t == 0){
    float ang = atan2f(zim, zre);
    float pidx = ang * (128.0f/(2.0f*(float)PI_D));
    sidx = ((int)rintf(pidx)) & 127;
  }
  __syncthreads();
  const int idx = sidx;
  if (u == idx && h == 0) speak = colu;
  __syncthreads();
  const float peak = speak;
  const float noise = (total - peak) * (1.0f/127.0f);

  if (isFinal){
    if (t == 0) atomicAdd(out, 10.0f*(log10f(peak) - log10f(noise)) * (1.0f/(float)BB));
    return;
  }

  constexpr float C10 = 4.342944819032518f;
  float g = (u == idx) ? (C10/peak) : (-C10/(127.0f*noise));
  __syncthreads();
  ysh[k] = make_float2(2.0f*g*Fr, 2.0f*g*Fi);
  __syncthreads();

  float Tr = 0.0f, Ti = 0.0f;
  #pragma unroll 8
  for (int q = 0; q < 64; ++q){
    int kk = h*64 + q;
    int id = (s*kk) & 127;
    float wr = twc[id], wi = -tws[id];
    float2 G = ysh[kk];
    Tr += wr*G.x - wi*G.y;
    Ti += wr*G.y + wi*G.x;
  }
  Tr += __shfl_xor(Tr, 1);
  Ti += __shfl_xor(Ti, 1);

  float Hr = xc.x*Tr + xc.y*Ti;
  float Hi = xc.x*Ti - xc.y*Tr;
  float dm   = Hr*cph - Hi*sph;
  float dphi = -m*(Hr*sph + Hi*cph);
  float S1 = bsum256(m*dm, red12, t) * 0.5f;
  float gwm = m*(dm - S1*(1.0f/128.0f));
  float gwp = dphi / (1.0f + wp0*wp0);

  constexpr float LN10 = 2.302585092994046f;
  float lrm = expf(lsm[s*NST + stepi] * LN10);
  float lrp = expf(lsp[s*NST + stepi] * LN10);
  float wm1 = wm0 + lrm*gwm;
  float wp1 = wp0 + lrp*gwp;
  if (h == 0){
    w_mag[b*SS + s] = wm1;
    w_phase[b*SS + s] = wp1;
  }

  float mx2 = bmax256(wm1, red12, t);
  float ex2 = expf(wm1 - mx2);
  float sm2 = bsum256(ex2, red12, t) * 0.5f;
  float m2 = 128.0f * ex2 / sm2;
  float phi2 = atanf(wp1);
  float s2v, c2v;
  sincosf(phi2, &s2v, &c2v);
  if (h == 0) cvec[b*SS + s] = make_float2(m2*c2v, -m2*s2v);
  if (t == 0) slots[b] = 0ull;
}

extern "C" void kernel_launch(void* const* d_in, const int* in_sizes, int n_in,
                              void* d_out, int out_size, void* d_ws, size_t ws_size,
                              hipStream_t stream)
{
  const float* x_re = (const float*)d_in[0];
  const float* x_im = (const float*)d_in[1];
  const float* k_re = (const float*)d_in[2];
  const float* k_im = (const float*)d_in[3];
  const float* lsm  = (const float*)d_in[4];
  const float* lsp  = (const float*)d_in[5];
  const float* wpi  = (const float*)d_in[6];
  float* out = (float*)d_out;

  char* ws = (char*)d_ws;
  size_t off = 0;
  float2* xmf = (float2*)(ws + off);                 off += (size_t)BB*SS*LL*sizeof(float2);
  unsigned long long* slots = (unsigned long long*)(ws + off); off += 256;
  float* w_mag   = (float*)(ws + off);               off += (size_t)BB*SS*4;
  float* w_phase = (float*)(ws + off);               off += (size_t)BB*SS*4;
  float2* cvec   = (float2*)(ws + off);              off += (size_t)BB*SS*8;
  const size_t off_base = off;
  float4* xt2 = (float4*)(ws + off);                 off += (size_t)BB*SS*LL*sizeof(float2);
  const int useT = (ws_size >= off) ? 1 : 0;
  if (ws_size < off_base) return;   // insufficient scratch -> fail visibly

  mf_kernel<<<BB*SS, 256, 0, stream>>>(x_re, x_im, k_re, k_im, xmf);
  init_kernel<<<(BB*SS + 255)/256, 256, 0, stream>>>(wpi, w_mag, w_phase, cvec, slots, out);

  if (useT){
    // fused transpose + iteration-0 scan
    tr_scan_kernel<<<dim3(LL/64, BB), 256, 0, stream>>>(xmf, xt2, cvec, slots);
    step_kernel<<<BB, 256, 0, stream>>>(xmf, w_mag, w_phase, cvec, slots, lsm, lsp, 0, 0, out);
    for (int i = 1; i < NST; i++){
      scan_t_kernel<<<dim3(LL/64, BB), 256, 0, stream>>>(xt2, cvec, slots);
      step_kernel<<<BB, 256, 0, stream>>>(xmf, w_mag, w_phase, cvec, slots, lsm, lsp, i, 0, out);
    }
    scan_t_kernel<<<dim3(LL/64, BB), 256, 0, stream>>>(xt2, cvec, slots);
    step_kernel<<<BB, 256, 0, stream>>>(xmf, w_mag, w_phase, cvec, slots, lsm, lsp, 0, 1, out);
  } else {
    for (int i = 0; i < NST; i++){
      scan_o_kernel<<<dim3(LL/128, BB), 512, 0, stream>>>(xmf, cvec, slots);
      step_kernel<<<BB, 256, 0, stream>>>(xmf, w_mag, w_phase, cvec, slots, lsm, lsp, i, 0, out);
    }
    scan_o_kernel<<<dim3(LL/128, BB), 512, 0, stream>>>(xmf, cvec, slots);
    step_kernel<<<BB, 256, 0, stream>>>(xmf, w_mag, w_phase, cvec, slots, lsm, lsp, 0, 1, out);
  }
}

// Round 13
// 757.912 us; speedup vs baseline: 1.0224x; 1.0015x over previous
//
#include <hip/hip_runtime.h>

#define BB 32
#define SS 128
#define LL 4096
#define KK 129
#define NST 10

typedef float v2f __attribute__((ext_vector_type(2)));

// ---------- constexpr twiddles: TW[j] = e^{-2*pi*i*j/128}, j in [0,64) ----------
constexpr double PI_D = 3.141592653589793238462643383279502884;
constexpr double red_sin(double x){ // |x| <= pi/2, Taylor to x^17
  double x2 = x*x, t = x, r = x;
  t *= -x2/6.0;   r += t;
  t *= -x2/20.0;  r += t;
  t *= -x2/42.0;  r += t;
  t *= -x2/72.0;  r += t;
  t *= -x2/110.0; r += t;
  t *= -x2/156.0; r += t;
  t *= -x2/210.0; r += t;
  t *= -x2/272.0; r += t;
  return r;
}
constexpr double csin_d(double x){
  while (x >  PI_D) x -= 2.0*PI_D;
  while (x < -PI_D) x += 2.0*PI_D;
  if (x >  PI_D*0.5)      x =  PI_D - x;
  else if (x < -PI_D*0.5) x = -PI_D - x;
  return red_sin(x);
}
constexpr double ccos_d(double x){ return csin_d(x + PI_D*0.5); }
struct TWT { float c[64]; float s[64]; };
constexpr TWT make_tw(){
  TWT t{};
  for (int j = 0; j < 64; j++){
    double a = -2.0*PI_D*(double)j/128.0;
    t.c[j] = (float)ccos_d(a);
    t.s[j] = (float)csin_d(a);
  }
  return t;
}
constexpr TWT TW = make_tw();

// LDS pads
#define PHYS16(i) ((i) + ((i) >> 4))    // +1 fl2 per 16 (t*16 stride -> 2t mod 32 banks, 4-way worst)

// packed complex MAC: acc.x += xv.x*w.x + xv.y*w.y ; acc.y += xv.y*w.x - xv.x*w.y
__device__ __forceinline__ void cfma_pk(v2f& acc, v2f xv, v2f w){
  asm("v_pk_fma_f32 %0, %1, %2, %0 op_sel:[0,0,0] op_sel_hi:[1,0,1]"
      : "+v"(acc) : "v"(xv), "v"(w));
  asm("v_pk_fma_f32 %0, %1, %2, %0 op_sel:[1,1,0] op_sel_hi:[0,1,1] neg_hi:[1,0,0]"
      : "+v"(acc) : "v"(xv), "v"(w));
}

// ---------- matched filter: full row per block, 32-slot ring, 16 outputs/thread ----------
// Refills now ds_read_b128 DIRECTLY into ring registers (no p0/p1 + v_mov commit):
// refill slots are disjoint from the chunk's live range and first read 3 chunks later.
__global__ __launch_bounds__(256) void mf_kernel(const float* __restrict__ xr,
                                                 const float* __restrict__ xi,
                                                 const float* __restrict__ kr,
                                                 const float* __restrict__ ki,
                                                 float2* __restrict__ out)
{
  const int row = blockIdx.x;             // b*S + s
  const int t   = threadIdx.x;            // 256
  __shared__ float2 xs[4488];             // xs[PHYS16(i)] = x[i - 64], i in [0, 4224)

  const float* xrr = xr + (size_t)row*LL;
  const float* xir = xi + (size_t)row*LL;
  for (int i4 = t; i4 < 1056; i4 += 256){ // 1056 groups of 4 float2
    const int g0 = i4*4 - 64;             // first float index
    float4 a, c;
    if (g0 >= 0 && g0 + 3 < LL){
      a = *(const float4*)(xrr + g0);
      c = *(const float4*)(xir + g0);
    } else {
      float av[4], cv[4];
      #pragma unroll
      for (int e = 0; e < 4; ++e){
        const int g = g0 + e;
        const bool ok = (g >= 0 && g < LL);
        av[e] = ok ? xrr[g] : 0.0f;
        cv[e] = ok ? xir[g] : 0.0f;
      }
      a = make_float4(av[0],av[1],av[2],av[3]);
      c = make_float4(cv[0],cv[1],cv[2],cv[3]);
    }
    const int p = PHYS16(i4*4);           // i4*4 % 16 in {0,4,8,12}: group stays in pad block
    xs[p]   = make_float2(a.x, c.x);
    xs[p+1] = make_float2(a.y, c.y);
    xs[p+2] = make_float2(a.z, c.z);
    xs[p+3] = make_float2(a.w, c.w);
  }
  __syncthreads();

  const int base_l = t*16;                // logical fl2 index of v=0
  // ring: slot (v&31) holds (re,im) of x[t*16 + v - 64]
  v2f ring[32];
  #pragma unroll
  for (int v = 0; v < 28; v += 2){        // preload v in [0,28) — direct to ring regs
    *(float4*)(&ring[v]) = *(const float4*)(&xs[PHYS16(base_l + v)]);
  }

  v2f acc[16];
  #pragma unroll
  for (int j = 0; j < 16; j++) acc[j] = (v2f){0.0f, 0.0f};

  // 32 chunks of 4 taps; chunk q reads v in [q*4, q*4+19]; refill fills [q*4+28, q*4+32)
  #pragma unroll 1
  for (int q16 = 0; q16 < 4; ++q16){
    #pragma unroll
    for (int qh = 0; qh < 2; ++qh){
      #pragma unroll
      for (int qq = 0; qq < 4; ++qq){
        const int q = q16*8 + qh*4 + qq;
        const bool doref = (q < 29);
        if (doref){
          const int v0 = base_l + q*4 + 28;
          const int s0 = (qh*16 + qq*4 + 28) & 31;  // {28,0,4,...,24}: +3 never wraps
          *(float4*)(&ring[s0])   = *(const float4*)(&xs[PHYS16(v0)]);
          *(float4*)(&ring[s0+2]) = *(const float4*)(&xs[PHYS16(v0 + 2)]);
        }
        #pragma unroll
        for (int kk = 0; kk < 4; ++kk){
          const v2f w = (v2f){ kr[q*4 + kk], ki[q*4 + kk] };  // uniform -> s_load
          #pragma unroll
          for (int j = 0; j < 16; ++j){
            const int sl = (qh*16 + qq*4 + kk + j) & 31;      // == (q*4+kk+j)&31
            cfma_pk(acc[j], ring[sl], w);
          }
        }
      }
    }
  }
  { // tap k = 128: v = 128+j -> slot j
    const v2f w = (v2f){ kr[128], ki[128] };
    #pragma unroll
    for (int j = 0; j < 16; ++j) cfma_pk(acc[j], ring[j], w);
  }

  float4* orow = (float4*)(out + (size_t)row*LL + base_l);
  #pragma unroll
  for (int q = 0; q < 8; ++q){
    orow[q] = make_float4(acc[2*q][0], acc[2*q][1], acc[2*q+1][0], acc[2*q+1][1]);
  }
}

// ---------- init ----------
__global__ void init_kernel(const float* __restrict__ wpi,
                            float* __restrict__ w_mag, float* __restrict__ w_phase,
                            float2* __restrict__ cvec, unsigned long long* __restrict__ slots,
                            float* __restrict__ out)
{
  const int i = blockIdx.x*256 + threadIdx.x;
  if (i < BB*SS){
    float wp = wpi[i];
    w_mag[i] = 1.0f;
    w_phase[i] = wp;
    float phi = atanf(wp);
    float s, c;
    sincosf(phi, &s, &c);
    cvec[i] = make_float2(c, -s);      // m = 1 exactly (softmax of equal values)
  }
  if (i < BB) slots[i] = 0ull;
  if (i == 0) out[0] = 0.0f;
}

// ---------- in-register FFT DIF stage over N points ----------
template<int SPAN, int N>
__device__ __forceinline__ void fstage(float2* v){
  #pragma unroll
  for (int b0 = 0; b0 < N; b0 += 2*SPAN){
    #pragma unroll
    for (int j = 0; j < SPAN; j++){
      const int i0 = b0 + j, i1 = b0 + j + SPAN;
      float ax = v[i0].x, ay = v[i0].y, bx = v[i1].x, by = v[i1].y;
      float sx = ax - bx, sy = ay - by;
      v[i0].x = ax + bx; v[i0].y = ay + by;
      const int tj = j * (64 / SPAN);   // W_{2*SPAN}^j = TW[tj]
      if (tj == 0){
        v[i1].x = sx; v[i1].y = sy;
      } else if (tj == 32){             // W = -i
        v[i1].x = sy; v[i1].y = -sx;
      } else {
        const float wr = TW.c[tj], wi = TW.s[tj];
        v[i1].x = sx*wr - sy*wi;
        v[i1].y = sy*wr + sx*wi;
      }
    }
  }
}

// ---------- FFT body (r2-validated, __shfl_xor form) ----------
__device__ __forceinline__ void scan_fft_tail(float2* v, int r, int tid, int l,
                                              unsigned long long* wred, int nwave,
                                              unsigned long long* slot)
{
  // stage 1 (span 64): partner = tid^2
  {
    const bool hi = (r & 2) != 0;
    const float sgn = hi ? -1.0f : 1.0f;
    const bool odd = (r & 1) != 0;
    #pragma unroll
    for (int j = 0; j < 32; ++j){
      float px = __shfl_xor(v[j].x, 2);
      float py = __shfl_xor(v[j].y, 2);
      float ux = fmaf(sgn, v[j].x, px);
      float uy = fmaf(sgn, v[j].y, py);
      float wr = hi ? (odd ? TW.s[j] : TW.c[j]) : 1.0f;   // r=3: W128^{32+j} = (s, -c)
      float wi = hi ? (odd ? -TW.c[j] : TW.s[j]) : 0.0f;
      v[j].x = ux*wr - uy*wi;
      v[j].y = uy*wr + ux*wi;
    }
  }
  // stage 2 (span 32): partner = tid^1
  {
    const bool hi = (r & 1) != 0;
    const float sgn = hi ? -1.0f : 1.0f;
    #pragma unroll
    for (int j = 0; j < 32; ++j){
      float px = __shfl_xor(v[j].x, 1);
      float py = __shfl_xor(v[j].y, 1);
      float ux = fmaf(sgn, v[j].x, px);
      float uy = fmaf(sgn, v[j].y, py);
      float wr = hi ? TW.c[2*j] : 1.0f;                   // W64^j = TW[2j]
      float wi = hi ? TW.s[2*j] : 0.0f;
      v[j].x = ux*wr - uy*wi;
      v[j].y = uy*wr + ux*wi;
    }
  }
  fstage<16,32>(v); fstage<8,32>(v); fstage<4,32>(v); fstage<2,32>(v); fstage<1,32>(v);

  float mm = 0.0f;
  #pragma unroll
  for (int j = 0; j < 32; ++j) mm = fmaxf(mm, v[j].x*v[j].x + v[j].y*v[j].y);
  mm = fmaxf(mm, __shfl_xor(mm, 1));
  mm = fmaxf(mm, __shfl_xor(mm, 2));

  unsigned long long pk = ((unsigned long long)__float_as_uint(mm) << 32) | (unsigned int)l;
  #pragma unroll
  for (int m = 4; m < 64; m <<= 1){
    unsigned long long o = __shfl_xor(pk, m);
    if (o > pk) pk = o;
  }
  if ((tid & 63) == 0) wred[tid >> 6] = pk;
  __syncthreads();
  if (tid == 0){
    unsigned long long best = wred[0];
    for (int w = 1; w < nwave; ++w) if (wred[w] > best) best = wred[w];
    atomicMax(slot, best);
  }
}

// ---------- fused transpose + iteration-0 scan (r10, validated) ----------
__global__ __launch_bounds__(256) void tr_scan_kernel(const float2* __restrict__ xmf,
                                                      float4* __restrict__ xt2,
                                                      const float2* __restrict__ cvec,
                                                      unsigned long long* __restrict__ slots)
{
  const int b = blockIdx.y;
  const int l0 = blockIdx.x * 64;
  const int tid = threadIdx.x;
  __shared__ float ldr[SS][65];
  __shared__ float ldi[SS][65];
  __shared__ float2 csh[SS];
  __shared__ unsigned long long wred[4];
  if (tid < SS) csh[tid] = cvec[b*SS + tid];

  #pragma unroll
  for (int it = 0; it < 16; ++it){
    const int flat = it*256 + tid;
    const int s  = flat >> 5;
    const int c4 = flat & 31;
    const float4 p = *(const float4*)(xmf + ((size_t)(b*SS + s))*LL + l0 + 2*c4);
    const int sw = 8*(s >> 5);
    ldr[s][(2*c4   + sw) & 63] = p.x;  ldi[s][(2*c4   + sw) & 63] = p.y;
    ldr[s][(2*c4+1 + sw) & 63] = p.z;  ldi[s][(2*c4+1 + sw) & 63] = p.w;
  }
  __syncthreads();

  float4* dst = xt2 + ((size_t)(b*256 + blockIdx.x*4) * 16) * 64;
  #pragma unroll
  for (int it = 0; it < 16; ++it){
    const int flat = it*256 + tid;
    const int lane = flat & 63;
    const int i   = (flat >> 6) & 15;
    const int lgl = flat >> 10;
    const int fl = lane >> 2, rr = lane & 3;
    const int lrow = lgl*16 + fl;
    const int s0 = rr*32 + 2*i;
    const int col = (lrow + 8*rr) & 63;
    dst[flat] = make_float4(ldr[s0][col], ldi[s0][col], ldr[s0+1][col], ldi[s0+1][col]);
  }

  const int f = tid >> 2, r = tid & 3;
  const int l = l0 + f;
  float2 v[32];
  #pragma unroll
  for (int j = 0; j < 32; ++j){
    const int rowi = r*32 + j;
    const int col = (f + 8*r) & 63;
    const float2 x = make_float2(ldr[rowi][col], ldi[rowi][col]);
    const float2 c = csh[rowi];
    v[j].x = c.x*x.x - c.y*x.y;
    v[j].y = c.x*x.y + c.y*x.x;
  }
  scan_fft_tail(v, r, tid, l, wred, 4, slots + b);
}

// ---------- scan (swizzled layout, r7 verbatim): contiguous 1KB wave-loads ----------
__global__ __launch_bounds__(256) void scan_t_kernel(const float4* __restrict__ xt2,
                                                     const float2* __restrict__ cvec,
                                                     unsigned long long* __restrict__ slots)
{
  const int b = blockIdx.y;
  const int tid = threadIdx.x;
  const int f = tid >> 2, r = tid & 3;   // 4 lanes per FFT
  const int l = blockIdx.x*64 + f;
  const int w = tid >> 6;                // wave id
  const int lg = blockIdx.x*4 + w;       // global 16-l group
  __shared__ float2 csh[SS];
  __shared__ unsigned long long wred[4];
  if (tid < SS) csh[tid] = cvec[b*SS + tid];
  __syncthreads();

  const float4* base = xt2 + ((size_t)(b*(LL/16) + lg) * 16) * 64 + (tid & 63);
  float2 v[32];
  #pragma unroll
  for (int i = 0; i < 16; ++i){          // v[j] = x[s = r*32 + j]
    const float4 p = base[i*64];
    v[2*i]   = make_float2(p.x, p.y);
    v[2*i+1] = make_float2(p.z, p.w);
  }
  #pragma unroll
  for (int j = 0; j < 32; ++j){
    const float2 c = csh[r*32 + j];
    const float2 x = v[j];
    v[j].x = c.x*x.x - c.y*x.y;
    v[j].y = c.x*x.y + c.y*x.x;
  }
  scan_fft_tail(v, r, tid, l, wred, 4, slots + b);
}

// ---------- scan (original layout, fallback if workspace too small) ----------
__global__ __launch_bounds__(512, 4) void scan_o_kernel(const float2* __restrict__ xmf,
                                                        const float2* __restrict__ cvec,
                                                        unsigned long long* __restrict__ slots)
{
  const int b = blockIdx.y;
  const int tid = threadIdx.x;
  const int l0 = blockIdx.x * 128;
  __shared__ float2 csh[SS];
  __shared__ float2 xsh[64][130];
  __shared__ unsigned long long wred[8];
  if (tid < SS) csh[tid] = cvec[b*SS + tid];

  const int f = tid >> 2, r = tid & 3;
  float2 v[32];

  #pragma unroll 1
  for (int h = 0; h < 2; ++h){
    __syncthreads();
    const float2* src = xmf + ((size_t)(b*SS + h*64))*LL + l0;
    #pragma unroll
    for (int it = 0; it < 8; ++it){
      const int flat = it*512 + tid;
      const int s1 = flat >> 6;
      const int c4 = flat & 63;
      const float4 vv = *(const float4*)(src + (size_t)s1*LL + c4*2);
      *(float4*)(&xsh[s1][c4*2]) = vv;
    }
    __syncthreads();
    if ((r >> 1) == h){
      #pragma unroll
      for (int j = 0; j < 32; ++j){
        const int rowi = (r & 1)*32 + j;
        const float2 x = xsh[rowi][f];
        const float2 c = csh[r*32 + j];
        v[j].x = c.x*x.x - c.y*x.y;
        v[j].y = c.x*x.y + c.y*x.x;
      }
    }
  }
  scan_fft_tail(v, r, tid, l0 + f, wred, 8, slots + b);
}

// ---------- wave + block (256 thr / 4 waves) reductions ----------
__device__ __forceinline__ float wredsum(float v){
  #pragma unroll
  for (int m = 1; m < 64; m <<= 1) v += __shfl_xor(v, m);
  return v;
}
__device__ __forceinline__ float wredmax(float v){
  #pragma unroll
  for (int m = 1; m < 64; m <<= 1) v = fmaxf(v, __shfl_xor(v, m));
  return v;
}
__device__ __forceinline__ float bsum256(float v, float* red, int t){
  v = wredsum(v);
  __syncthreads();
  if ((t & 63) == 0) red[t >> 6] = v;
  __syncthreads();
  return red[0] + red[1] + red[2] + red[3];
}
__device__ __forceinline__ float bmax256(float v, float* red, int t){
  v = wredmax(v);
  __syncthreads();
  if ((t & 63) == 0) red[t >> 6] = v;
  __syncthreads();
  return fmaxf(fmaxf(red[0], red[1]), fmaxf(red[2], red[3]));
}
// fused triple sum: per-component summation order identical to bsum256 (bit-exact)
__device__ __forceinline__ void bsum3_256(float a0, float a1, float a2,
                                          float* red12, int t,
                                          float& s0, float& s1, float& s2){
  #pragma unroll
  for (int m = 1; m < 64; m <<= 1){
    a0 += __shfl_xor(a0, m);
    a1 += __shfl_xor(a1, m);
    a2 += __shfl_xor(a2, m);
  }
  __syncthreads();
  if ((t & 63) == 0){
    const int w = t >> 6;
    red12[w] = a0; red12[w+4] = a1; red12[w+8] = a2;
  }
  __syncthreads();
  s0 = red12[0]+red12[1]+red12[2]+red12[3];
  s1 = red12[4]+red12[5]+red12[6]+red12[7];
  s2 = red12[8]+red12[9]+red12[10]+red12[11];
}

// ---------- per-step gradient + update (or final SNR); one block per b, 256 threads ----------
__global__ __launch_bounds__(256) void step_kernel(const float2* __restrict__ xmf,
                                                   float* __restrict__ w_mag,
                                                   float* __restrict__ w_phase,
                                                   float2* __restrict__ cvec,
                                                   unsigned long long* __restrict__ slots,
                                                   const float* __restrict__ lsm,
                                                   const float* __restrict__ lsp,
                                                   int stepi, int isFinal,
                                                   float* __restrict__ out)
{
  const int b = blockIdx.x, t = threadIdx.x;
  const int s = t >> 1, h = t & 1;
  __shared__ float2 ysh[SS];
  __shared__ float twc[SS], tws[SS];
  __shared__ float red12[12];
  __shared__ float speak;
  __shared__ int sidx;

  const int rbin = (int)(slots[b] & 0xffffffffull);
  const float wm0 = w_mag[b*SS + s];
  const float wp0 = w_phase[b*SS + s];
  const float2 xc = xmf[((size_t)(b*SS + s))*LL + rbin];
  float phi = atanf(wp0);
  float sph, cph;
  sincosf(phi, &sph, &cph);
  {
    // e^{-2 pi i id/128} from the constexpr table (id>=64: negate the id-64 entry)
    const int id = t & 127;
    const int lo = id & 63;
    const float sgn2 = (id < 64) ? 1.0f : -1.0f;
    twc[id] = sgn2 * TW.c[lo];
    tws[id] = sgn2 * TW.s[lo];
  }
  float mx = bmax256(wm0, red12, t);
  float ex = expf(wm0 - mx);
  float sm = bsum256(ex, red12, t) * 0.5f;
  float m = 128.0f * ex / sm;
  float cre = m*cph, cim = -m*sph;
  ysh[s] = make_float2(cre*xc.x - cim*xc.y, cre*xc.y + cim*xc.x);
  __syncthreads();

  const int k = s;
  float Fr = 0.0f, Fi = 0.0f;
  #pragma unroll 8
  for (int q = 0; q < 64; ++q){
    int s2 = h*64 + q;
    int id = (k*s2) & 127;
    float wr = twc[id], wi = tws[id];
    float2 ys = ysh[s2];
    Fr += wr*ys.x - wi*ys.y;
    Fi += wr*ys.y + wi*ys.x;
  }
  Fr += __shfl_xor(Fr, 1);
  Fi += __shfl_xor(Fi, 1);
  const int u = (k + 64) & 127;
  float colu = Fr*Fr + Fi*Fi;

  float total, zre, zim;
  bsum3_256(colu, colu * twc[u], colu * (-tws[u]), red12, t, total, zre, zim);
  total *= 0.5f; zre *= 0.5f; zim *= 0.5f;
  if (t == 0){
    float ang = atan2f(zim, zre);
    float pidx = ang * (128.0f/(2.0f*(float)PI_D));
    sidx = ((int)rintf(pidx)) & 127;
  }
  __syncthreads();
  const int idx = sidx;
  if (u == idx && h == 0) speak = colu;
  __syncthreads();
  const float peak = speak;
  const float noise = (total - peak) * (1.0f/127.0f);

  if (isFinal){
    if (t == 0) atomicAdd(out, 10.0f*(log10f(peak) - log10f(noise)) * (1.0f/(float)BB));
    return;
  }

  constexpr float C10 = 4.342944819032518f;
  float g = (u == idx) ? (C10/peak) : (-C10/(127.0f*noise));
  __syncthreads();
  ysh[k] = make_float2(2.0f*g*Fr, 2.0f*g*Fi);
  __syncthreads();

  float Tr = 0.0f, Ti = 0.0f;
  #pragma unroll 8
  for (int q = 0; q < 64; ++q){
    int kk = h*64 + q;
    int id = (s*kk) & 127;
    float wr = twc[id], wi = -tws[id];
    float2 G = ysh[kk];
    Tr += wr*G.x - wi*G.y;
    Ti += wr*G.y + wi*G.x;
  }
  Tr += __shfl_xor(Tr, 1);
  Ti += __shfl_xor(Ti, 1);

  float Hr = xc.x*Tr + xc.y*Ti;
  float Hi = xc.x*Ti - xc.y*Tr;
  float dm   = Hr*cph - Hi*sph;
  float dphi = -m*(Hr*sph + Hi*cph);
  float S1 = bsum256(m*dm, red12, t) * 0.5f;
  float gwm = m*(dm - S1*(1.0f/128.0f));
  float gwp = dphi / (1.0f + wp0*wp0);

  constexpr float LN10 = 2.302585092994046f;
  float lrm = expf(lsm[s*NST + stepi] * LN10);
  float lrp = expf(lsp[s*NST + stepi] * LN10);
  float wm1 = wm0 + lrm*gwm;
  float wp1 = wp0 + lrp*gwp;
  if (h == 0){
    w_mag[b*SS + s] = wm1;
    w_phase[b*SS + s] = wp1;
  }

  float mx2 = bmax256(wm1, red12, t);
  float ex2 = expf(wm1 - mx2);
  float sm2 = bsum256(ex2, red12, t) * 0.5f;
  float m2 = 128.0f * ex2 / sm2;
  float phi2 = atanf(wp1);
  float s2v, c2v;
  sincosf(phi2, &s2v, &c2v);
  if (h == 0) cvec[b*SS + s] = make_float2(m2*c2v, -m2*s2v);
  if (t == 0) slots[b] = 0ull;
}

extern "C" void kernel_launch(void* const* d_in, const int* in_sizes, int n_in,
                              void* d_out, int out_size, void* d_ws, size_t ws_size,
                              hipStream_t stream)
{
  const float* x_re = (const float*)d_in[0];
  const float* x_im = (const float*)d_in[1];
  const float* k_re = (const float*)d_in[2];
  const float* k_im = (const float*)d_in[3];
  const float* lsm  = (const float*)d_in[4];
  const float* lsp  = (const float*)d_in[5];
  const float* wpi  = (const float*)d_in[6];
  float* out = (float*)d_out;

  char* ws = (char*)d_ws;
  size_t off = 0;
  float2* xmf = (float2*)(ws + off);                 off += (size_t)BB*SS*LL*sizeof(float2);
  unsigned long long* slots = (unsigned long long*)(ws + off); off += 256;
  float* w_mag   = (float*)(ws + off);               off += (size_t)BB*SS*4;
  float* w_phase = (float*)(ws + off);               off += (size_t)BB*SS*4;
  float2* cvec   = (float2*)(ws + off);              off += (size_t)BB*SS*8;
  const size_t off_base = off;
  float4* xt2 = (float4*)(ws + off);                 off += (size_t)BB*SS*LL*sizeof(float2);
  const int useT = (ws_size >= off) ? 1 : 0;
  if (ws_size < off_base) return;   // insufficient scratch -> fail visibly

  mf_kernel<<<BB*SS, 256, 0, stream>>>(x_re, x_im, k_re, k_im, xmf);
  init_kernel<<<(BB*SS + 255)/256, 256, 0, stream>>>(wpi, w_mag, w_phase, cvec, slots, out);

  if (useT){
    // fused transpose + iteration-0 scan
    tr_scan_kernel<<<dim3(LL/64, BB), 256, 0, stream>>>(xmf, xt2, cvec, slots);
    step_kernel<<<BB, 256, 0, stream>>>(xmf, w_mag, w_phase, cvec, slots, lsm, lsp, 0, 0, out);
    for (int i = 1; i < NST; i++){
      scan_t_kernel<<<dim3(LL/64, BB), 256, 0, stream>>>(xt2, cvec, slots);
      step_kernel<<<BB, 256, 0, stream>>>(xmf, w_mag, w_phase, cvec, slots, lsm, lsp, i, 0, out);
    }
    scan_t_kernel<<<dim3(LL/64, BB), 256, 0, stream>>>(xt2, cvec, slots);
    step_kernel<<<BB, 256, 0, stream>>>(xmf, w_mag, w_phase, cvec, slots, lsm, lsp, 0, 1, out);
  } else {
    for (int i = 0; i < NST; i++){
      scan_o_kernel<<<dim3(LL/128, BB), 512, 0, stream>>>(xmf, cvec, slots);
      step_kernel<<<BB, 256, 0, stream>>>(xmf, w_mag, w_phase, cvec, slots, lsm, lsp, i, 0, out);
    }
    scan_o_kernel<<<dim3(LL/128, BB), 512, 0, stream>>>(xmf, cvec, slots);
    step_kernel<<<BB, 256, 0, stream>>>(xmf, w_mag, w_phase, cvec, slots, lsm, lsp, 0, 1, out);
  }
}